// Round 15
// baseline (119.899 us; speedup 1.0000x reference)
//
#include <hip/hip_runtime.h>
#include <math.h>

#define T_LEN 1024
#define VV 512
#define BB 64
#define NB 16
#define ANG_STEP 0.006135923151542565f   // 2*pi/1024
#define FADE_S 487
#define FADE_E 537

typedef float v4f __attribute__((ext_vector_type(4)));   // native vec for nontemporal stores

__device__ constexpr int KB[NB] = {1,2,3,4,5,6,7,8,12,16,24,32,48,64,96,128};
// cs(t+512) = (-1)^k * cs(t): sign per bin (k odd -> -1)
__device__ constexpr float SGN[NB] = {-1.f, 1.f, -1.f, 1.f, -1.f, 1.f, -1.f, 1.f,
                                       1.f, 1.f,  1.f, 1.f,  1.f, 1.f,  1.f, 1.f};

// ---------------- Fused kernel: DFT + combine + apply, one block per (b, v-slice) ----------------
// grid (BB, 4), block 512 = 32 v-threads (VPT=4, v0 = vc*128 + vt*4) x 16 t-groups (64 rows each).
// Phase 1: per-lane 16-bin DFT over its 64 t rows (cs from 512-row LDS table + sign trick).
// Reduction: 4 rounds through LDS scratch (aliased over tab); H -> LDS + global (for fixup).
// Phase 2: re-read x (L3-resident) + apply with register H. Fade rows fixed by k_fixup after.
__global__ __launch_bounds__(512, 1) void k_fused(const float* __restrict__ x,
                                                  const float* __restrict__ ger,
                                                  const float* __restrict__ gei,
                                                  const float* __restrict__ glr,
                                                  const float* __restrict__ gli,
                                                  float* __restrict__ Hg,
                                                  float* __restrict__ out) {
    const int b   = blockIdx.x;
    const int vc  = blockIdx.y;
    const int tid = threadIdx.x;
    const int vt  = tid & 31;
    const int th  = tid >> 5;

    __shared__ __align__(16) float2 tab[512][NB];   // 64 KB; aliased as reduction scratch
    __shared__ __align__(16) float  HB[64 * 128];   // 32 KB: HB[q][v_local]
    float* scr = (float*)tab;

    // build cs table for t in [0,512)
    for (int i = tid; i < 512 * NB; i += 512) {
        int t = i >> 4, j = i & 15;
        int idx = (KB[j] * t) & (T_LEN - 1);
        float ss, cc; sincosf(ANG_STEP * (float)idx, &ss, &cc);
        tab[t][j] = make_float2(cc, ss);
    }
    __syncthreads();

    // ---- phase 1: DFT over own 64 t rows ----
    float ar[4][NB], ai[4][NB];
#pragma unroll
    for (int k = 0; k < 4; ++k)
#pragma unroll
        for (int j = 0; j < NB; ++j) { ar[k][j] = 0.f; ai[k][j] = 0.f; }

    const int tbase = th * 64;
    const int ttab  = tbase & 511;
    const float4* xrd = (const float4*)(x + ((size_t)b * T_LEN + tbase) * VV + vc * 128) + vt;

#define DFT_T(TT, AV)                                           \
    do {                                                        \
        _Pragma("unroll")                                       \
        for (int j = 0; j < NB; ++j) {                          \
            float2 cs = tab[ttab + (TT)][j];                    \
            ar[0][j] = fmaf((AV).x, cs.x, ar[0][j]);            \
            ai[0][j] = fmaf(-(AV).x, cs.y, ai[0][j]);           \
            ar[1][j] = fmaf((AV).y, cs.x, ar[1][j]);            \
            ai[1][j] = fmaf(-(AV).y, cs.y, ai[1][j]);           \
            ar[2][j] = fmaf((AV).z, cs.x, ar[2][j]);            \
            ai[2][j] = fmaf(-(AV).z, cs.y, ai[2][j]);           \
            ar[3][j] = fmaf((AV).w, cs.x, ar[3][j]);            \
            ai[3][j] = fmaf(-(AV).w, cs.y, ai[3][j]);           \
        }                                                       \
    } while (0)

    {
        float4 a0 = xrd[(size_t)0 * 128];
        float4 a1 = xrd[(size_t)1 * 128];
        float4 a2 = xrd[(size_t)2 * 128];
        float4 a3 = xrd[(size_t)3 * 128];
#pragma unroll 1
        for (int i = 0; i < 60; i += 4) {
            float4 b0 = xrd[(size_t)(i + 4) * 128];
            float4 b1 = xrd[(size_t)(i + 5) * 128];
            float4 b2 = xrd[(size_t)(i + 6) * 128];
            float4 b3 = xrd[(size_t)(i + 7) * 128];
            DFT_T(i + 0, a0); DFT_T(i + 1, a1); DFT_T(i + 2, a2); DFT_T(i + 3, a3);
            a0 = b0; a1 = b1; a2 = b2; a3 = b3;
        }
        DFT_T(60, a0); DFT_T(61, a1); DFT_T(62, a2); DFT_T(63, a3);
    }
#undef DFT_T

    // sign correction for t >= 512 rows
    if (th >= 8) {
#pragma unroll
        for (int k = 0; k < 4; ++k)
#pragma unroll
            for (int j = 0; j < NB; ++j) { ar[k][j] *= SGN[j]; ai[k][j] *= SGN[j]; }
    }

    __syncthreads();   // tab reads done; scr may be overwritten

    // ---- reduction + H: 4 rounds of 4 bins each ----
    const float scale = 2.0f / (float)T_LEN;
#pragma unroll
    for (int r = 0; r < 4; ++r) {
        const int j0 = r * 4;
#pragma unroll
        for (int k = 0; k < 4; ++k) {
            const int v = vt * 4 + k;
            float4* w = (float4*)(scr + (size_t)(th * 128 + v) * 8);
            w[0] = make_float4(ar[k][j0 + 0], ar[k][j0 + 1], ar[k][j0 + 2], ar[k][j0 + 3]);
            w[1] = make_float4(ai[k][j0 + 0], ai[k][j0 + 1], ai[k][j0 + 2], ai[k][j0 + 3]);
        }
        __syncthreads();
        {
            const int v  = tid & 127;
            const int jj = tid >> 7;
            const int j  = j0 + jj;
            float Xre = 0.f, Xim = 0.f;
#pragma unroll
            for (int t2 = 0; t2 < 16; ++t2) {
                Xre += scr[(size_t)(t2 * 128 + v) * 8 + jj];
                Xim += scr[(size_t)(t2 * 128 + v) * 8 + 4 + jj];
            }
            const int vg = vc * 128 + v;
            float er = ger[vg * NB + j], ei = gei[vg * NB + j];
            float lr = glr[vg * NB + j], li = gli[vg * NB + j];
            float here  = (Xre * er - Xim * ei) * scale;
            float heimN = -(Xre * ei + Xim * er) * scale;
            float hlre  = (Xre * lr - Xim * li) * scale;
            float hlimN = -(Xre * li + Xim * lr) * scale;
            HB[j * 128 + v]        = here;
            HB[(16 + j) * 128 + v] = heimN;
            HB[(32 + j) * 128 + v] = hlre;
            HB[(48 + j) * 128 + v] = hlimN;
            float* hg = Hg + (size_t)b * 64 * VV + vg;
            hg[(size_t)j * VV]        = here;
            hg[(size_t)(16 + j) * VV] = heimN;
            hg[(size_t)(32 + j) * VV] = hlre;
            hg[(size_t)(48 + j) * VV] = hlimN;
        }
        __syncthreads();
    }

    // rebuild cs table (scratch overwrote it)
    for (int i = tid; i < 512 * NB; i += 512) {
        int t = i >> 4, j = i & 15;
        int idx = (KB[j] * t) & (T_LEN - 1);
        float ss, cc; sincosf(ANG_STEP * (float)idx, &ss, &cc);
        tab[t][j] = make_float2(cc, ss);
    }
    __syncthreads();

    // ---- phase 2: apply with register H (He for t<512, Hl for t>=512; sign folded) ----
    float hr0[NB], hr1[NB], hr2[NB], hr3[NB];
    float hi0[NB], hi1[NB], hi2[NB], hi3[NB];
    const int qb = (th < 8) ? 0 : 32;
#pragma unroll
    for (int j = 0; j < NB; ++j) {
        const float4 a  = *(const float4*)&HB[(qb + j)      * 128 + vt * 4];
        const float4 bq = *(const float4*)&HB[(qb + 16 + j) * 128 + vt * 4];
        const float sg = (th >= 8) ? SGN[j] : 1.0f;
        hr0[j] = a.x * sg;  hr1[j] = a.y * sg;  hr2[j] = a.z * sg;  hr3[j] = a.w * sg;
        hi0[j] = bq.x * sg; hi1[j] = bq.y * sg; hi2[j] = bq.z * sg; hi3[j] = bq.w * sg;
    }

    v4f* ow = (v4f*)(out + ((size_t)b * T_LEN + tbase) * VV + vc * 128) + vt;

#define APPLY_T(TT, AV)                                               \
    do {                                                              \
        float s0 = 0.f, s1 = 0.f, s2 = 0.f, s3 = 0.f;                 \
        _Pragma("unroll")                                             \
        for (int j = 0; j < NB; ++j) {                                \
            float2 cs = tab[ttab + (TT)][j];                          \
            s0 = fmaf(hr0[j], cs.x, s0); s0 = fmaf(hi0[j], cs.y, s0); \
            s1 = fmaf(hr1[j], cs.x, s1); s1 = fmaf(hi1[j], cs.y, s1); \
            s2 = fmaf(hr2[j], cs.x, s2); s2 = fmaf(hi2[j], cs.y, s2); \
            s3 = fmaf(hr3[j], cs.x, s3); s3 = fmaf(hi3[j], cs.y, s3); \
        }                                                             \
        v4f ov; ov.x = (AV).x + s0; ov.y = (AV).y + s1;               \
        ov.z = (AV).z + s2; ov.w = (AV).w + s3;                       \
        __builtin_nontemporal_store(ov, &ow[(size_t)(TT) * 128]);     \
    } while (0)

    {
        float4 a0 = xrd[(size_t)0 * 128];
        float4 a1 = xrd[(size_t)1 * 128];
        float4 a2 = xrd[(size_t)2 * 128];
        float4 a3 = xrd[(size_t)3 * 128];
#pragma unroll 1
        for (int i = 0; i < 60; i += 4) {
            float4 b0 = xrd[(size_t)(i + 4) * 128];
            float4 b1 = xrd[(size_t)(i + 5) * 128];
            float4 b2 = xrd[(size_t)(i + 6) * 128];
            float4 b3 = xrd[(size_t)(i + 7) * 128];
            APPLY_T(i + 0, a0); APPLY_T(i + 1, a1); APPLY_T(i + 2, a2); APPLY_T(i + 3, a3);
            a0 = b0; a1 = b1; a2 = b2; a3 = b3;
        }
        APPLY_T(60, a0); APPLY_T(61, a1); APPLY_T(62, a2); APPLY_T(63, a3);
    }
#undef APPLY_T
}

// ---------------- Fade fixup, rows 487..536 only (exact dual-H crossfade) ----------------
// grid (BB, 2), block 512, thread owns v = tid.
__global__ __launch_bounds__(512) void k_fixup(const float* __restrict__ x,
                                               const float* __restrict__ H,
                                               float* __restrict__ out) {
    const int b   = blockIdx.x;
    const int tz  = blockIdx.y;
    const int tid = threadIdx.x;
    const int ts  = tz ? 512 : FADE_S;
    const int te  = tz ? FADE_E : 512;
    const int nt  = te - ts;                   // 25 rows each

    __shared__ float2 tab[32][NB];
    for (int i = tid; i < nt * NB; i += 512) {
        int t = i >> 4, j = i & 15;
        int idx = (KB[j] * (ts + t)) & (T_LEN - 1);
        float ss, cc; sincosf(ANG_STEP * (float)idx, &ss, &cc);
        tab[t][j] = make_float2(cc, ss);
    }

    float er[NB], ei[NB], lr[NB], li[NB];
    const float* hp = H + (size_t)b * 64 * VV + tid;
#pragma unroll
    for (int j = 0; j < NB; ++j) {
        er[j] = hp[(size_t)j        * VV];
        ei[j] = hp[(size_t)(16 + j) * VV];
        lr[j] = hp[(size_t)(32 + j) * VV];
        li[j] = hp[(size_t)(48 + j) * VV];
    }
    __syncthreads();

    const float* xrd = x + ((size_t)b * T_LEN + ts) * VV + tid;
    float*       ow  = out + ((size_t)b * T_LEN + ts) * VV + tid;

    for (int t = 0; t < nt; ++t) {
        float av = xrd[(size_t)t * VV];
        const int tg = ts + t;
        float se = 0.f, sl = 0.f;
#pragma unroll
        for (int j = 0; j < NB; ++j) {
            float2 cs = tab[t][j];
            se = fmaf(er[j], cs.x, se); se = fmaf(ei[j], cs.y, se);
            sl = fmaf(lr[j], cs.x, sl); sl = fmaf(li[j], cs.y, sl);
        }
        float w = 1.0f - (float)(tg - FADE_S) * (1.0f / 50.0f);
        ow[(size_t)t * VV] = av + fmaf(w, se - sl, sl);
    }
}

extern "C" void kernel_launch(void* const* d_in, const int* in_sizes, int n_in,
                              void* d_out, int out_size, void* d_ws, size_t ws_size,
                              hipStream_t stream) {
    (void)in_sizes; (void)n_in; (void)out_size; (void)ws_size;
    const float* x   = (const float*)d_in[0];
    const float* ger = (const float*)d_in[1];
    const float* gei = (const float*)d_in[2];
    const float* glr = (const float*)d_in[3];
    const float* gli = (const float*)d_in[4];
    float* out = (float*)d_out;

    float* Hg = (float*)d_ws;    // BB*64*VV floats = 8.4 MB

    k_fused<<<dim3(BB, 4), 512, 0, stream>>>(x, ger, gei, glr, gli, Hg, out);
    k_fixup<<<dim3(BB, 2), 512, 0, stream>>>(x, Hg, out);
}

// Round 16
// 114.628 us; speedup vs baseline: 1.0460x; 1.0460x over previous
//
#include <hip/hip_runtime.h>
#include <math.h>

#define T_LEN 1024
#define VV 512
#define BB 64
#define NB 16
#define ANG_STEP 0.006135923151542565f   // 2*pi/1024
#define FADE_S 487
#define FADE_E 537

typedef float v2f __attribute__((ext_vector_type(2)));   // native vec for nontemporal stores

__device__ constexpr int KB[NB] = {1,2,3,4,5,6,7,8,12,16,24,32,48,64,96,128};
// cs(t+512) = (-1)^k * cs(t): sign per bin (k odd -> -1)
__device__ constexpr float SGN[NB] = {-1.f, 1.f, -1.f, 1.f, -1.f, 1.f, -1.f, 1.f,
                                       1.f, 1.f,  1.f, 1.f,  1.f, 1.f,  1.f, 1.f};

// ---------------- Fused kernel v2 ----------------
// grid (BB, 4), block 512 = 8 waves. Wave w owns t-rows [w*128, w*128+128) for the
// block's 128-v slice (lane owns v0 = vc*128 + lane*2, VPT=2).
// - tab[512][NB] (64 KB), sign trick for t>=512; tab reads are WAVE-UNIFORM broadcasts.
// - Reduction over the 8 waves via padded LDS scratch (stride 17: no 32-way conflicts),
//   two rounds (re, im); waves 4..7 accumulate in place (RMW).
// - H written to global only (no LDS H buffer); phase 2 re-reads it through L2.
// - Phase 2 re-reads x (L3-resident after phase 1) and applies with register H.
// Fade rows 487..536 are overwritten by k_fixup afterwards.
__global__ __launch_bounds__(512, 1) void k_fused(const float* __restrict__ x,
                                                  const float* __restrict__ ger,
                                                  const float* __restrict__ gei,
                                                  const float* __restrict__ glr,
                                                  const float* __restrict__ gli,
                                                  float* __restrict__ Hg,
                                                  float* __restrict__ out) {
    const int b    = blockIdx.x;
    const int vc   = blockIdx.y;
    const int tid  = threadIdx.x;
    const int wave = tid >> 6;
    const int lane = tid & 63;

    __shared__ __align__(16) float2 tab[512][NB];   // 64 KB; rows 0..272 aliased as scr
    float* scr = (float*)tab;                        // scr[(w*128 + v)*17 + j], w<4

    for (int i = tid; i < 512 * NB; i += 512) {
        int t = i >> 4, j = i & 15;
        int idx = (KB[j] * t) & (T_LEN - 1);
        float ss, cc; sincosf(ANG_STEP * (float)idx, &ss, &cc);
        tab[t][j] = make_float2(cc, ss);
    }
    __syncthreads();

    // ---- phase 1: per-wave DFT over its 128 t rows ----
    float ar0[NB], ai0[NB], ar1[NB], ai1[NB];
#pragma unroll
    for (int j = 0; j < NB; ++j) { ar0[j] = ai0[j] = ar1[j] = ai1[j] = 0.f; }

    const int trow = wave * 128;
    const int ttab = trow & 511;
    const float2* xrd = (const float2*)(x + ((size_t)b * T_LEN + trow) * VV + vc * 128) + lane;

#define DFT_T(TT, AV)                                           \
    do {                                                        \
        _Pragma("unroll")                                       \
        for (int j = 0; j < NB; ++j) {                          \
            float2 cs = tab[ttab + (TT)][j];                    \
            ar0[j] = fmaf((AV).x, cs.x, ar0[j]);                \
            ai0[j] = fmaf(-(AV).x, cs.y, ai0[j]);               \
            ar1[j] = fmaf((AV).y, cs.x, ar1[j]);                \
            ai1[j] = fmaf(-(AV).y, cs.y, ai1[j]);               \
        }                                                       \
    } while (0)

    {
        float2 a0 = xrd[(size_t)0 * 256];
        float2 a1 = xrd[(size_t)1 * 256];
        float2 a2 = xrd[(size_t)2 * 256];
        float2 a3 = xrd[(size_t)3 * 256];
        float2 a4 = xrd[(size_t)4 * 256];
        float2 a5 = xrd[(size_t)5 * 256];
        float2 a6 = xrd[(size_t)6 * 256];
        float2 a7 = xrd[(size_t)7 * 256];
#pragma unroll 1
        for (int i = 0; i < 120; i += 8) {
            float2 b0 = xrd[(size_t)(i +  8) * 256];
            float2 b1 = xrd[(size_t)(i +  9) * 256];
            float2 b2 = xrd[(size_t)(i + 10) * 256];
            float2 b3 = xrd[(size_t)(i + 11) * 256];
            float2 b4 = xrd[(size_t)(i + 12) * 256];
            float2 b5 = xrd[(size_t)(i + 13) * 256];
            float2 b6 = xrd[(size_t)(i + 14) * 256];
            float2 b7 = xrd[(size_t)(i + 15) * 256];
            DFT_T(i + 0, a0); DFT_T(i + 1, a1); DFT_T(i + 2, a2); DFT_T(i + 3, a3);
            DFT_T(i + 4, a4); DFT_T(i + 5, a5); DFT_T(i + 6, a6); DFT_T(i + 7, a7);
            a0 = b0; a1 = b1; a2 = b2; a3 = b3;
            a4 = b4; a5 = b5; a6 = b6; a7 = b7;
        }
        DFT_T(120, a0); DFT_T(121, a1); DFT_T(122, a2); DFT_T(123, a3);
        DFT_T(124, a4); DFT_T(125, a5); DFT_T(126, a6); DFT_T(127, a7);
    }
#undef DFT_T

    if (wave >= 4) {
#pragma unroll
        for (int j = 0; j < NB; ++j) {
            ar0[j] *= SGN[j]; ai0[j] *= SGN[j];
            ar1[j] *= SGN[j]; ai1[j] *= SGN[j];
        }
    }
    __syncthreads();   // phase-1 tab reads done; scr region reusable

    // ---- reduction: round 1 (re), round 2 (im) ----
    const int v0 = lane * 2;
    float Xre[4], Xim[4];

    if (wave < 4) {
#pragma unroll
        for (int j = 0; j < NB; ++j) {
            scr[((size_t)wave * 128 + v0)     * 17 + j] = ar0[j];
            scr[((size_t)wave * 128 + v0 + 1) * 17 + j] = ar1[j];
        }
    }
    __syncthreads();
    if (wave >= 4) {
        const int w2 = wave - 4;
#pragma unroll
        for (int j = 0; j < NB; ++j) {
            scr[((size_t)w2 * 128 + v0)     * 17 + j] += ar0[j];
            scr[((size_t)w2 * 128 + v0 + 1) * 17 + j] += ar1[j];
        }
    }
    __syncthreads();
#pragma unroll
    for (int q = 0; q < 4; ++q) {
        const int c = tid * 4 + q;
        const int vq = c >> 4, jq = c & 15;
        Xre[q] = scr[((size_t)0 * 128 + vq) * 17 + jq]
               + scr[((size_t)1 * 128 + vq) * 17 + jq]
               + scr[((size_t)2 * 128 + vq) * 17 + jq]
               + scr[((size_t)3 * 128 + vq) * 17 + jq];
    }
    __syncthreads();

    if (wave < 4) {
#pragma unroll
        for (int j = 0; j < NB; ++j) {
            scr[((size_t)wave * 128 + v0)     * 17 + j] = ai0[j];
            scr[((size_t)wave * 128 + v0 + 1) * 17 + j] = ai1[j];
        }
    }
    __syncthreads();
    if (wave >= 4) {
        const int w2 = wave - 4;
#pragma unroll
        for (int j = 0; j < NB; ++j) {
            scr[((size_t)w2 * 128 + v0)     * 17 + j] += ai0[j];
            scr[((size_t)w2 * 128 + v0 + 1) * 17 + j] += ai1[j];
        }
    }
    __syncthreads();
#pragma unroll
    for (int q = 0; q < 4; ++q) {
        const int c = tid * 4 + q;
        const int vq = c >> 4, jq = c & 15;
        Xim[q] = scr[((size_t)0 * 128 + vq) * 17 + jq]
               + scr[((size_t)1 * 128 + vq) * 17 + jq]
               + scr[((size_t)2 * 128 + vq) * 17 + jq]
               + scr[((size_t)3 * 128 + vq) * 17 + jq];
    }
    __syncthreads();   // scr reads done (tab rebuild may overwrite)

    // ---- H compute -> global ----
    const float scale = 2.0f / (float)T_LEN;
    {
        float* hg = Hg + (size_t)b * 64 * VV;
#pragma unroll
        for (int q = 0; q < 4; ++q) {
            const int c = tid * 4 + q;
            const int vq = c >> 4, jq = c & 15;
            const int vg = vc * 128 + vq;
            float er = ger[vg * NB + jq], ei = gei[vg * NB + jq];
            float lr = glr[vg * NB + jq], li = gli[vg * NB + jq];
            float here  = (Xre[q] * er - Xim[q] * ei) * scale;
            float heimN = -(Xre[q] * ei + Xim[q] * er) * scale;
            float hlre  = (Xre[q] * lr - Xim[q] * li) * scale;
            float hlimN = -(Xre[q] * li + Xim[q] * lr) * scale;
            hg[(size_t)jq * VV + vg]        = here;
            hg[(size_t)(16 + jq) * VV + vg] = heimN;
            hg[(size_t)(32 + jq) * VV + vg] = hlre;
            hg[(size_t)(48 + jq) * VV + vg] = hlimN;
        }
    }

    // rebuild tab rows 0..272 (overwritten by scr)
    __syncthreads();
    for (int i = tid; i < 273 * NB; i += 512) {
        int t = i >> 4, j = i & 15;
        int idx = (KB[j] * t) & (T_LEN - 1);
        float ss, cc; sincosf(ANG_STEP * (float)idx, &ss, &cc);
        tab[t][j] = make_float2(cc, ss);
    }
    __syncthreads();   // also makes Hg writes visible block-wide

    // ---- phase 2: apply (He waves 0..3, Hl waves 4..7; sign folded into H) ----
    float hr0[NB], hi0[NB], hr1[NB], hi1[NB];
    {
        const int qb = (wave < 4) ? 0 : 32;
        const float* hgr = Hg + (size_t)b * 64 * VV + vc * 128;
#pragma unroll
        for (int j = 0; j < NB; ++j) {
            const float sg = (wave >= 4) ? SGN[j] : 1.0f;
            hr0[j] = hgr[(size_t)(qb + j) * VV + v0]          * sg;
            hr1[j] = hgr[(size_t)(qb + j) * VV + v0 + 1]      * sg;
            hi0[j] = hgr[(size_t)(qb + 16 + j) * VV + v0]     * sg;
            hi1[j] = hgr[(size_t)(qb + 16 + j) * VV + v0 + 1] * sg;
        }
    }

    v2f* ow = (v2f*)(out + ((size_t)b * T_LEN + trow) * VV + vc * 128) + lane;

#define APPLY_T(TT, AV)                                               \
    do {                                                              \
        float s0 = 0.f, s1 = 0.f;                                     \
        _Pragma("unroll")                                             \
        for (int j = 0; j < NB; ++j) {                                \
            float2 cs = tab[ttab + (TT)][j];                          \
            s0 = fmaf(hr0[j], cs.x, s0); s0 = fmaf(hi0[j], cs.y, s0); \
            s1 = fmaf(hr1[j], cs.x, s1); s1 = fmaf(hi1[j], cs.y, s1); \
        }                                                             \
        v2f ov; ov.x = (AV).x + s0; ov.y = (AV).y + s1;               \
        __builtin_nontemporal_store(ov, &ow[(size_t)(TT) * 256]);     \
    } while (0)

    {
        float2 a0 = xrd[(size_t)0 * 256];
        float2 a1 = xrd[(size_t)1 * 256];
        float2 a2 = xrd[(size_t)2 * 256];
        float2 a3 = xrd[(size_t)3 * 256];
        float2 a4 = xrd[(size_t)4 * 256];
        float2 a5 = xrd[(size_t)5 * 256];
        float2 a6 = xrd[(size_t)6 * 256];
        float2 a7 = xrd[(size_t)7 * 256];
#pragma unroll 1
        for (int i = 0; i < 120; i += 8) {
            float2 b0 = xrd[(size_t)(i +  8) * 256];
            float2 b1 = xrd[(size_t)(i +  9) * 256];
            float2 b2 = xrd[(size_t)(i + 10) * 256];
            float2 b3 = xrd[(size_t)(i + 11) * 256];
            float2 b4 = xrd[(size_t)(i + 12) * 256];
            float2 b5 = xrd[(size_t)(i + 13) * 256];
            float2 b6 = xrd[(size_t)(i + 14) * 256];
            float2 b7 = xrd[(size_t)(i + 15) * 256];
            APPLY_T(i + 0, a0); APPLY_T(i + 1, a1); APPLY_T(i + 2, a2); APPLY_T(i + 3, a3);
            APPLY_T(i + 4, a4); APPLY_T(i + 5, a5); APPLY_T(i + 6, a6); APPLY_T(i + 7, a7);
            a0 = b0; a1 = b1; a2 = b2; a3 = b3;
            a4 = b4; a5 = b5; a6 = b6; a7 = b7;
        }
        APPLY_T(120, a0); APPLY_T(121, a1); APPLY_T(122, a2); APPLY_T(123, a3);
        APPLY_T(124, a4); APPLY_T(125, a5); APPLY_T(126, a6); APPLY_T(127, a7);
    }
#undef APPLY_T
}

// ---------------- Fade fixup, rows 487..536 only (exact dual-H crossfade) ----------------
// grid (BB, 2), block 512, thread owns v = tid.
__global__ __launch_bounds__(512) void k_fixup(const float* __restrict__ x,
                                               const float* __restrict__ H,
                                               float* __restrict__ out) {
    const int b   = blockIdx.x;
    const int tz  = blockIdx.y;
    const int tid = threadIdx.x;
    const int ts  = tz ? 512 : FADE_S;
    const int te  = tz ? FADE_E : 512;
    const int nt  = te - ts;                   // 25 rows each

    __shared__ float2 tab[32][NB];
    for (int i = tid; i < nt * NB; i += 512) {
        int t = i >> 4, j = i & 15;
        int idx = (KB[j] * (ts + t)) & (T_LEN - 1);
        float ss, cc; sincosf(ANG_STEP * (float)idx, &ss, &cc);
        tab[t][j] = make_float2(cc, ss);
    }

    float er[NB], ei[NB], lr[NB], li[NB];
    const float* hp = H + (size_t)b * 64 * VV + tid;
#pragma unroll
    for (int j = 0; j < NB; ++j) {
        er[j] = hp[(size_t)j        * VV];
        ei[j] = hp[(size_t)(16 + j) * VV];
        lr[j] = hp[(size_t)(32 + j) * VV];
        li[j] = hp[(size_t)(48 + j) * VV];
    }
    __syncthreads();

    const float* xrd = x + ((size_t)b * T_LEN + ts) * VV + tid;
    float*       ow  = out + ((size_t)b * T_LEN + ts) * VV + tid;

    for (int t = 0; t < nt; ++t) {
        float av = xrd[(size_t)t * VV];
        const int tg = ts + t;
        float se = 0.f, sl = 0.f;
#pragma unroll
        for (int j = 0; j < NB; ++j) {
            float2 cs = tab[t][j];
            se = fmaf(er[j], cs.x, se); se = fmaf(ei[j], cs.y, se);
            sl = fmaf(lr[j], cs.x, sl); sl = fmaf(li[j], cs.y, sl);
        }
        float w = 1.0f - (float)(tg - FADE_S) * (1.0f / 50.0f);
        ow[(size_t)t * VV] = av + fmaf(w, se - sl, sl);
    }
}

extern "C" void kernel_launch(void* const* d_in, const int* in_sizes, int n_in,
                              void* d_out, int out_size, void* d_ws, size_t ws_size,
                              hipStream_t stream) {
    (void)in_sizes; (void)n_in; (void)out_size; (void)ws_size;
    const float* x   = (const float*)d_in[0];
    const float* ger = (const float*)d_in[1];
    const float* gei = (const float*)d_in[2];
    const float* glr = (const float*)d_in[3];
    const float* gli = (const float*)d_in[4];
    float* out = (float*)d_out;

    float* Hg = (float*)d_ws;    // BB*64*VV floats = 8.4 MB

    k_fused<<<dim3(BB, 4), 512, 0, stream>>>(x, ger, gei, glr, gli, Hg, out);
    k_fixup<<<dim3(BB, 2), 512, 0, stream>>>(x, Hg, out);
}

// Round 17
// 108.187 us; speedup vs baseline: 1.1083x; 1.0595x over previous
//
#include <hip/hip_runtime.h>
#include <math.h>

#define T_LEN 1024
#define VV 512
#define BB 64
#define NB 16
#define ANG_STEP 0.006135923151542565f   // 2*pi/1024
#define FADE_S 487
#define FADE_E 537

typedef float v2f __attribute__((ext_vector_type(2)));   // native vec for nontemporal stores

__device__ constexpr int KB[NB] = {1,2,3,4,5,6,7,8,12,16,24,32,48,64,96,128};
// cs(t+512) = (-1)^k * cs(t): sign per bin (k odd -> -1)
__device__ constexpr float SGN[NB] = {-1.f, 1.f, -1.f, 1.f, -1.f, 1.f, -1.f, 1.f,
                                       1.f, 1.f,  1.f, 1.f,  1.f, 1.f,  1.f, 1.f};

// ---------------- Fused kernel v3: 2-bin-packed cs table ----------------
// grid (BB, 4), block 512 = 8 waves. Wave w owns t-rows [w*128, w*128+128) of the
// block's 128-v slice (lane owns v0 = vc*128 + lane*2, VPT=2).
// tab4[t][m] = (cos(2m), sin(2m), cos(2m+1), sin(2m+1)) -> 8 ds_read_b128 per
// t-step instead of 16 ds_read_b64 (halves LDS-pipe instruction issue, the R16
// bottleneck: ~41us/phase). scr is a SEPARATE LDS region (no alias, no rebuild).
// Fade rows 487..536 are overwritten by k_fixup afterwards.
__global__ __launch_bounds__(512, 1) void k_fused(const float* __restrict__ x,
                                                  const float* __restrict__ ger,
                                                  const float* __restrict__ gei,
                                                  const float* __restrict__ glr,
                                                  const float* __restrict__ gli,
                                                  float* __restrict__ Hg,
                                                  float* __restrict__ out) {
    const int b    = blockIdx.x;
    const int vc   = blockIdx.y;
    const int tid  = threadIdx.x;
    const int wave = tid >> 6;
    const int lane = tid & 63;

    __shared__ __align__(16) float4 tab4[512][8];            // 64 KB
    __shared__ __align__(16) float  scr[4 * 128 * 17];       // 34 KB reduction scratch

    for (int i = tid; i < 512 * 8; i += 512) {
        int t = i >> 3, m = i & 7;
        int j0 = 2 * m, j1 = 2 * m + 1;
        int idx0 = (KB[j0] * t) & (T_LEN - 1);
        int idx1 = (KB[j1] * t) & (T_LEN - 1);
        float s0, c0, s1, c1;
        sincosf(ANG_STEP * (float)idx0, &s0, &c0);
        sincosf(ANG_STEP * (float)idx1, &s1, &c1);
        tab4[t][m] = make_float4(c0, s0, c1, s1);
    }
    __syncthreads();

    // ---- phase 1: per-wave DFT over its 128 t rows ----
    float ar0[NB], ai0[NB], ar1[NB], ai1[NB];
#pragma unroll
    for (int j = 0; j < NB; ++j) { ar0[j] = ai0[j] = ar1[j] = ai1[j] = 0.f; }

    const int trow = wave * 128;
    const int ttab = trow & 511;
    const float2* xrd = (const float2*)(x + ((size_t)b * T_LEN + trow) * VV + vc * 128) + lane;

#define DFT_T(TT, AV)                                               \
    do {                                                            \
        _Pragma("unroll")                                           \
        for (int m = 0; m < 8; ++m) {                               \
            float4 cs = tab4[ttab + (TT)][m];                       \
            ar0[2*m]   = fmaf((AV).x, cs.x, ar0[2*m]);              \
            ai0[2*m]   = fmaf(-(AV).x, cs.y, ai0[2*m]);             \
            ar1[2*m]   = fmaf((AV).y, cs.x, ar1[2*m]);              \
            ai1[2*m]   = fmaf(-(AV).y, cs.y, ai1[2*m]);             \
            ar0[2*m+1] = fmaf((AV).x, cs.z, ar0[2*m+1]);            \
            ai0[2*m+1] = fmaf(-(AV).x, cs.w, ai0[2*m+1]);           \
            ar1[2*m+1] = fmaf((AV).y, cs.z, ar1[2*m+1]);            \
            ai1[2*m+1] = fmaf(-(AV).y, cs.w, ai1[2*m+1]);           \
        }                                                           \
    } while (0)

    {
        float2 a0 = xrd[(size_t)0 * 256];
        float2 a1 = xrd[(size_t)1 * 256];
        float2 a2 = xrd[(size_t)2 * 256];
        float2 a3 = xrd[(size_t)3 * 256];
        float2 a4 = xrd[(size_t)4 * 256];
        float2 a5 = xrd[(size_t)5 * 256];
        float2 a6 = xrd[(size_t)6 * 256];
        float2 a7 = xrd[(size_t)7 * 256];
#pragma unroll 1
        for (int i = 0; i < 120; i += 8) {
            float2 b0 = xrd[(size_t)(i +  8) * 256];
            float2 b1 = xrd[(size_t)(i +  9) * 256];
            float2 b2 = xrd[(size_t)(i + 10) * 256];
            float2 b3 = xrd[(size_t)(i + 11) * 256];
            float2 b4 = xrd[(size_t)(i + 12) * 256];
            float2 b5 = xrd[(size_t)(i + 13) * 256];
            float2 b6 = xrd[(size_t)(i + 14) * 256];
            float2 b7 = xrd[(size_t)(i + 15) * 256];
            DFT_T(i + 0, a0); DFT_T(i + 1, a1); DFT_T(i + 2, a2); DFT_T(i + 3, a3);
            DFT_T(i + 4, a4); DFT_T(i + 5, a5); DFT_T(i + 6, a6); DFT_T(i + 7, a7);
            a0 = b0; a1 = b1; a2 = b2; a3 = b3;
            a4 = b4; a5 = b5; a6 = b6; a7 = b7;
        }
        DFT_T(120, a0); DFT_T(121, a1); DFT_T(122, a2); DFT_T(123, a3);
        DFT_T(124, a4); DFT_T(125, a5); DFT_T(126, a6); DFT_T(127, a7);
    }
#undef DFT_T

    if (wave >= 4) {
#pragma unroll
        for (int j = 0; j < NB; ++j) {
            ar0[j] *= SGN[j]; ai0[j] *= SGN[j];
            ar1[j] *= SGN[j]; ai1[j] *= SGN[j];
        }
    }
    __syncthreads();

    // ---- reduction: round 1 (re), round 2 (im) ----
    const int v0 = lane * 2;
    float Xre[4], Xim[4];

    if (wave < 4) {
#pragma unroll
        for (int j = 0; j < NB; ++j) {
            scr[((size_t)wave * 128 + v0)     * 17 + j] = ar0[j];
            scr[((size_t)wave * 128 + v0 + 1) * 17 + j] = ar1[j];
        }
    }
    __syncthreads();
    if (wave >= 4) {
        const int w2 = wave - 4;
#pragma unroll
        for (int j = 0; j < NB; ++j) {
            scr[((size_t)w2 * 128 + v0)     * 17 + j] += ar0[j];
            scr[((size_t)w2 * 128 + v0 + 1) * 17 + j] += ar1[j];
        }
    }
    __syncthreads();
#pragma unroll
    for (int q = 0; q < 4; ++q) {
        const int c = tid * 4 + q;
        const int vq = c >> 4, jq = c & 15;
        Xre[q] = scr[((size_t)0 * 128 + vq) * 17 + jq]
               + scr[((size_t)1 * 128 + vq) * 17 + jq]
               + scr[((size_t)2 * 128 + vq) * 17 + jq]
               + scr[((size_t)3 * 128 + vq) * 17 + jq];
    }
    __syncthreads();

    if (wave < 4) {
#pragma unroll
        for (int j = 0; j < NB; ++j) {
            scr[((size_t)wave * 128 + v0)     * 17 + j] = ai0[j];
            scr[((size_t)wave * 128 + v0 + 1) * 17 + j] = ai1[j];
        }
    }
    __syncthreads();
    if (wave >= 4) {
        const int w2 = wave - 4;
#pragma unroll
        for (int j = 0; j < NB; ++j) {
            scr[((size_t)w2 * 128 + v0)     * 17 + j] += ai0[j];
            scr[((size_t)w2 * 128 + v0 + 1) * 17 + j] += ai1[j];
        }
    }
    __syncthreads();
#pragma unroll
    for (int q = 0; q < 4; ++q) {
        const int c = tid * 4 + q;
        const int vq = c >> 4, jq = c & 15;
        Xim[q] = scr[((size_t)0 * 128 + vq) * 17 + jq]
               + scr[((size_t)1 * 128 + vq) * 17 + jq]
               + scr[((size_t)2 * 128 + vq) * 17 + jq]
               + scr[((size_t)3 * 128 + vq) * 17 + jq];
    }

    // ---- H compute -> global ----
    const float scale = 2.0f / (float)T_LEN;
    {
        float* hg = Hg + (size_t)b * 64 * VV;
#pragma unroll
        for (int q = 0; q < 4; ++q) {
            const int c = tid * 4 + q;
            const int vq = c >> 4, jq = c & 15;
            const int vg = vc * 128 + vq;
            float er = ger[vg * NB + jq], ei = gei[vg * NB + jq];
            float lr = glr[vg * NB + jq], li = gli[vg * NB + jq];
            float here  = (Xre[q] * er - Xim[q] * ei) * scale;
            float heimN = -(Xre[q] * ei + Xim[q] * er) * scale;
            float hlre  = (Xre[q] * lr - Xim[q] * li) * scale;
            float hlimN = -(Xre[q] * li + Xim[q] * lr) * scale;
            hg[(size_t)jq * VV + vg]        = here;
            hg[(size_t)(16 + jq) * VV + vg] = heimN;
            hg[(size_t)(32 + jq) * VV + vg] = hlre;
            hg[(size_t)(48 + jq) * VV + vg] = hlimN;
        }
    }
    __syncthreads();   // Hg writes visible block-wide before phase-2 reads

    // ---- phase 2: apply (He waves 0..3, Hl waves 4..7; sign folded into H) ----
    float hr0[NB], hi0[NB], hr1[NB], hi1[NB];
    {
        const int qb = (wave < 4) ? 0 : 32;
        const float* hgr = Hg + (size_t)b * 64 * VV + vc * 128;
#pragma unroll
        for (int j = 0; j < NB; ++j) {
            const float sg = (wave >= 4) ? SGN[j] : 1.0f;
            hr0[j] = hgr[(size_t)(qb + j) * VV + v0]          * sg;
            hr1[j] = hgr[(size_t)(qb + j) * VV + v0 + 1]      * sg;
            hi0[j] = hgr[(size_t)(qb + 16 + j) * VV + v0]     * sg;
            hi1[j] = hgr[(size_t)(qb + 16 + j) * VV + v0 + 1] * sg;
        }
    }

    v2f* ow = (v2f*)(out + ((size_t)b * T_LEN + trow) * VV + vc * 128) + lane;

#define APPLY_T(TT, AV)                                                       \
    do {                                                                      \
        float s0 = 0.f, s1 = 0.f;                                             \
        _Pragma("unroll")                                                     \
        for (int m = 0; m < 8; ++m) {                                         \
            float4 cs = tab4[ttab + (TT)][m];                                 \
            s0 = fmaf(hr0[2*m], cs.x, s0);   s0 = fmaf(hi0[2*m], cs.y, s0);   \
            s1 = fmaf(hr1[2*m], cs.x, s1);   s1 = fmaf(hi1[2*m], cs.y, s1);   \
            s0 = fmaf(hr0[2*m+1], cs.z, s0); s0 = fmaf(hi0[2*m+1], cs.w, s0); \
            s1 = fmaf(hr1[2*m+1], cs.z, s1); s1 = fmaf(hi1[2*m+1], cs.w, s1); \
        }                                                                     \
        v2f ov; ov.x = (AV).x + s0; ov.y = (AV).y + s1;                       \
        __builtin_nontemporal_store(ov, &ow[(size_t)(TT) * 256]);             \
    } while (0)

    {
        float2 a0 = xrd[(size_t)0 * 256];
        float2 a1 = xrd[(size_t)1 * 256];
        float2 a2 = xrd[(size_t)2 * 256];
        float2 a3 = xrd[(size_t)3 * 256];
        float2 a4 = xrd[(size_t)4 * 256];
        float2 a5 = xrd[(size_t)5 * 256];
        float2 a6 = xrd[(size_t)6 * 256];
        float2 a7 = xrd[(size_t)7 * 256];
#pragma unroll 1
        for (int i = 0; i < 120; i += 8) {
            float2 b0 = xrd[(size_t)(i +  8) * 256];
            float2 b1 = xrd[(size_t)(i +  9) * 256];
            float2 b2 = xrd[(size_t)(i + 10) * 256];
            float2 b3 = xrd[(size_t)(i + 11) * 256];
            float2 b4 = xrd[(size_t)(i + 12) * 256];
            float2 b5 = xrd[(size_t)(i + 13) * 256];
            float2 b6 = xrd[(size_t)(i + 14) * 256];
            float2 b7 = xrd[(size_t)(i + 15) * 256];
            APPLY_T(i + 0, a0); APPLY_T(i + 1, a1); APPLY_T(i + 2, a2); APPLY_T(i + 3, a3);
            APPLY_T(i + 4, a4); APPLY_T(i + 5, a5); APPLY_T(i + 6, a6); APPLY_T(i + 7, a7);
            a0 = b0; a1 = b1; a2 = b2; a3 = b3;
            a4 = b4; a5 = b5; a6 = b6; a7 = b7;
        }
        APPLY_T(120, a0); APPLY_T(121, a1); APPLY_T(122, a2); APPLY_T(123, a3);
        APPLY_T(124, a4); APPLY_T(125, a5); APPLY_T(126, a6); APPLY_T(127, a7);
    }
#undef APPLY_T
}

// ---------------- Fade fixup, rows 487..536 only (exact dual-H crossfade) ----------------
// grid (BB, 2), block 512, thread owns v = tid.
__global__ __launch_bounds__(512) void k_fixup(const float* __restrict__ x,
                                               const float* __restrict__ H,
                                               float* __restrict__ out) {
    const int b   = blockIdx.x;
    const int tz  = blockIdx.y;
    const int tid = threadIdx.x;
    const int ts  = tz ? 512 : FADE_S;
    const int te  = tz ? FADE_E : 512;
    const int nt  = te - ts;                   // 25 rows each

    __shared__ float2 tab[32][NB];
    for (int i = tid; i < nt * NB; i += 512) {
        int t = i >> 4, j = i & 15;
        int idx = (KB[j] * (ts + t)) & (T_LEN - 1);
        float ss, cc; sincosf(ANG_STEP * (float)idx, &ss, &cc);
        tab[t][j] = make_float2(cc, ss);
    }

    float er[NB], ei[NB], lr[NB], li[NB];
    const float* hp = H + (size_t)b * 64 * VV + tid;
#pragma unroll
    for (int j = 0; j < NB; ++j) {
        er[j] = hp[(size_t)j        * VV];
        ei[j] = hp[(size_t)(16 + j) * VV];
        lr[j] = hp[(size_t)(32 + j) * VV];
        li[j] = hp[(size_t)(48 + j) * VV];
    }
    __syncthreads();

    const float* xrd = x + ((size_t)b * T_LEN + ts) * VV + tid;
    float*       ow  = out + ((size_t)b * T_LEN + ts) * VV + tid;

    for (int t = 0; t < nt; ++t) {
        float av = xrd[(size_t)t * VV];
        const int tg = ts + t;
        float se = 0.f, sl = 0.f;
#pragma unroll
        for (int j = 0; j < NB; ++j) {
            float2 cs = tab[t][j];
            se = fmaf(er[j], cs.x, se); se = fmaf(ei[j], cs.y, se);
            sl = fmaf(lr[j], cs.x, sl); sl = fmaf(li[j], cs.y, sl);
        }
        float w = 1.0f - (float)(tg - FADE_S) * (1.0f / 50.0f);
        ow[(size_t)t * VV] = av + fmaf(w, se - sl, sl);
    }
}

extern "C" void kernel_launch(void* const* d_in, const int* in_sizes, int n_in,
                              void* d_out, int out_size, void* d_ws, size_t ws_size,
                              hipStream_t stream) {
    (void)in_sizes; (void)n_in; (void)out_size; (void)ws_size;
    const float* x   = (const float*)d_in[0];
    const float* ger = (const float*)d_in[1];
    const float* gei = (const float*)d_in[2];
    const float* glr = (const float*)d_in[3];
    const float* gli = (const float*)d_in[4];
    float* out = (float*)d_out;

    float* Hg = (float*)d_ws;    // BB*64*VV floats = 8.4 MB

    k_fused<<<dim3(BB, 4), 512, 0, stream>>>(x, ger, gei, glr, gli, Hg, out);
    k_fixup<<<dim3(BB, 2), 512, 0, stream>>>(x, Hg, out);
}